// Round 1
// baseline (4181.478 us; speedup 1.0000x reference)
//
#include <hip/hip_runtime.h>
#include <math.h>

// OnlineClustering: x[4,4096,768] f32, W[8192,768] f32
// out = assignments[4,4096,8192] f32 ++ loss[1] f32
//
// Pipeline:
//  K0 normalize rows of x -> xn (ws)
//  K1 fp32 GEMM: logits[row,k] = xn[row,:]·W[k,:]  (row = s*4096+b), 512MB in ws
//  K2 column max over b (two-stage partials)  -> offv[s,k] = 50 - 20*colmax
//  SK as diagonal scalings: M = E * CS[k] * RS[b],  E = exp(20*logit + offv)
//  c1 -> r1 -> c2 -> r2 -> c3 via reduction passes; final pass computes r3,
//  writes assignments, and accumulates the CE loss (log_softmax at temp 0.12).

#define S_DIM 4
#define B_DIM 4096
#define D_DIM 768
#define K_DIM 8192
#define ROWS (S_DIM * B_DIM)   // 16384
#define BCHUNK 16
#define BPER (B_DIM / BCHUNK)  // 256
#define SK_EPS 1e-8f

__device__ __forceinline__ float block_reduce_sum(float v, float* sbuf) {
  #pragma unroll
  for (int off = 32; off > 0; off >>= 1) v += __shfl_down(v, off, 64);
  int lane = threadIdx.x & 63, wid = threadIdx.x >> 6;
  __syncthreads();
  if (lane == 0) sbuf[wid] = v;
  __syncthreads();
  return sbuf[0] + sbuf[1] + sbuf[2] + sbuf[3];
}

__device__ __forceinline__ float block_reduce_max(float v, float* sbuf) {
  #pragma unroll
  for (int off = 32; off > 0; off >>= 1) v = fmaxf(v, __shfl_down(v, off, 64));
  int lane = threadIdx.x & 63, wid = threadIdx.x >> 6;
  __syncthreads();
  if (lane == 0) sbuf[wid] = v;
  __syncthreads();
  return fmaxf(fmaxf(sbuf[0], sbuf[1]), fmaxf(sbuf[2], sbuf[3]));
}

// ---------------- K0: L2-normalize feature rows ----------------
__global__ __launch_bounds__(256) void normalize_rows(const float* __restrict__ x,
                                                      float* __restrict__ xn) {
  __shared__ float sbuf[4];
  size_t row = blockIdx.x;
  const float* xr = x + row * D_DIM;
  float ss = 0.f;
  for (int i = threadIdx.x; i < D_DIM; i += 256) { float v = xr[i]; ss += v * v; }
  ss = block_reduce_sum(ss, sbuf);
  float inv = 1.0f / fmaxf(sqrtf(ss), 1e-7f);
  float* xo = xn + row * D_DIM;
  for (int i = threadIdx.x; i < D_DIM; i += 256) xo[i] = xr[i] * inv;
}

// ---------------- K1: fp32 GEMM C[M,N] = A[M,768] * B[N,768]^T ----------------
__global__ __launch_bounds__(256) void gemm_nt(const float* __restrict__ A,
                                               const float* __restrict__ B,
                                               float* __restrict__ C) {
  __shared__ float As[16][68];
  __shared__ float Bs[16][68];
  const int tid = threadIdx.x;
  const int bn = blockIdx.x * 64;  // over K_DIM
  const int bm = blockIdx.y * 64;  // over ROWS
  const int tx = tid & 15, ty = tid >> 4;
  float acc[4][4] = {};
  const float* Ab = A + (size_t)bm * D_DIM;
  const float* Bb = B + (size_t)bn * D_DIM;
  for (int k0 = 0; k0 < D_DIM; k0 += 16) {
    #pragma unroll
    for (int i = 0; i < 4; i++) {
      int idx = tid + i * 256;
      int m = idx >> 4, kk = idx & 15;
      As[kk][m] = Ab[(size_t)m * D_DIM + k0 + kk];
      Bs[kk][m] = Bb[(size_t)m * D_DIM + k0 + kk];
    }
    __syncthreads();
    #pragma unroll
    for (int kk = 0; kk < 16; kk++) {
      const float4 a4 = *(const float4*)&As[kk][4 * ty];
      const float4 b4 = *(const float4*)&Bs[kk][4 * tx];
      const float a[4] = {a4.x, a4.y, a4.z, a4.w};
      const float b[4] = {b4.x, b4.y, b4.z, b4.w};
      #pragma unroll
      for (int i = 0; i < 4; i++)
        #pragma unroll
        for (int j = 0; j < 4; j++)
          acc[i][j] = fmaf(a[i], b[j], acc[i][j]);
    }
    __syncthreads();
  }
  #pragma unroll
  for (int i = 0; i < 4; i++) {
    float4 o = {acc[i][0], acc[i][1], acc[i][2], acc[i][3]};
    *(float4*)&C[(size_t)(bm + 4 * ty + i) * K_DIM + bn + 4 * tx] = o;
  }
}

// ---------------- K2: column max partials (over b) ----------------
__global__ __launch_bounds__(256) void col_max_partial(const float* __restrict__ logits,
                                                       float* __restrict__ pbuf) {
  int k = blockIdx.x * 256 + threadIdx.x;
  int chunk = blockIdx.y, s = blockIdx.z;
  const float* base = logits + ((size_t)s * B_DIM + (size_t)chunk * BPER) * K_DIM + k;
  float mx = -INFINITY;
  #pragma unroll 4
  for (int b = 0; b < BPER; b++) mx = fmaxf(mx, base[(size_t)b * K_DIM]);
  pbuf[((size_t)chunk * S_DIM + s) * K_DIM + k] = mx;
}

__global__ __launch_bounds__(256) void col_max_reduce(const float* __restrict__ pbuf,
                                                      float* __restrict__ offv) {
  int i = blockIdx.x * 256 + threadIdx.x;  // i = s*K_DIM + k, over 32768
  int s = i >> 13, k = i & (K_DIM - 1);
  float mx = -INFINITY;
  for (int c = 0; c < BCHUNK; c++) mx = fmaxf(mx, pbuf[((size_t)c * S_DIM + s) * K_DIM + k]);
  offv[i] = 50.0f - 20.0f * mx;
}

// ---------------- column sum partials: sum_b E * (RS[b] or 1) ----------------
__global__ __launch_bounds__(256) void col_sum_partial(const float* __restrict__ logits,
                                                       const float* __restrict__ offv,
                                                       const float* __restrict__ RS, int use_rs,
                                                       float* __restrict__ pbuf) {
  int k = blockIdx.x * 256 + threadIdx.x;
  int chunk = blockIdx.y, s = blockIdx.z;
  const float off = offv[(size_t)s * K_DIM + k];
  const float* base = logits + ((size_t)s * B_DIM + (size_t)chunk * BPER) * K_DIM + k;
  const float* rs = RS + (size_t)s * B_DIM + (size_t)chunk * BPER;
  float sum = 0.f;
  #pragma unroll 4
  for (int b = 0; b < BPER; b++) {
    float e = __expf(fmaf(20.0f, base[(size_t)b * K_DIM], off));
    float rfac = use_rs ? rs[b] : 1.0f;
    sum += e * rfac;
  }
  pbuf[((size_t)chunk * S_DIM + s) * K_DIM + k] = sum;
}

// reduce partials; CS_new = CS_old / (CS_old * sum + eps)
__global__ __launch_bounds__(256) void col_sum_reduce(const float* __restrict__ pbuf,
                                                      float* __restrict__ CS, int init) {
  int i = blockIdx.x * 256 + threadIdx.x;
  int s = i >> 13, k = i & (K_DIM - 1);
  float ssum = 0.f;
  for (int c = 0; c < BCHUNK; c++) ssum += pbuf[((size_t)c * S_DIM + s) * K_DIM + k];
  float old = init ? 1.0f : CS[i];
  CS[i] = old / (fmaf(old, ssum, SK_EPS));
}

// ---------------- row pass: RS_new = RS_old / (RS_old * sum_k(E*CS) + eps) ----------------
__global__ __launch_bounds__(256) void row_pass(const float* __restrict__ logits,
                                                const float* __restrict__ offv,
                                                const float* __restrict__ CS,
                                                float* __restrict__ RS, int init) {
  __shared__ float sbuf[4];
  int b = blockIdx.x, s = blockIdx.y;
  size_t row = (size_t)s * B_DIM + b;
  const float* lg = logits + row * K_DIM;
  const float* of = offv + (size_t)s * K_DIM;
  const float* cs = CS + (size_t)s * K_DIM;
  float sum = 0.f;
  #pragma unroll 4
  for (int k = threadIdx.x; k < K_DIM; k += 256) {
    float e = __expf(fmaf(20.0f, lg[k], of[k]));
    sum += e * cs[k];
  }
  sum = block_reduce_sum(sum, sbuf);
  if (threadIdx.x == 0) {
    float old = init ? 1.0f : RS[row];
    RS[row] = old / fmaf(old, sum, SK_EPS);
  }
}

// ---------------- final: r3 + write assignments + loss ----------------
__global__ __launch_bounds__(256) void final_pass(const float* __restrict__ logits,
                                                  const float* __restrict__ offv,
                                                  const float* __restrict__ CS,
                                                  const float* __restrict__ RS,
                                                  float* __restrict__ out,
                                                  double* __restrict__ loss_acc) {
  __shared__ float sbuf[4];
  int b = blockIdx.x, s = blockIdx.y;
  size_t row = (size_t)s * B_DIM + b;
  const float* lg = logits + row * K_DIM;
  const float* of = offv + (size_t)s * K_DIM;
  const float* cs = CS + (size_t)s * K_DIM;
  float r = RS[row];
  float sum = 0.f, mx = -INFINITY;
  #pragma unroll 4
  for (int k = threadIdx.x; k < K_DIM; k += 256) {
    float lgk = lg[k];
    float e = __expf(fmaf(20.0f, lgk, of[k])) * cs[k];
    sum += e;
    mx = fmaxf(mx, lgk);
  }
  sum = block_reduce_sum(sum, sbuf);   // sum_k E*CS
  mx = block_reduce_max(mx, sbuf);     // row max of logits
  float rowsum = r * sum;
  float r3 = 1.0f / (rowsum + SK_EPS);
  float fac = r * r3;
  float sumtgt = rowsum * r3;
  const float qs = 1.0f / 0.12f;
  float Z = 0.f, dot = 0.f;
  float* orow = out + row * K_DIM;
  #pragma unroll 2
  for (int k = threadIdx.x; k < K_DIM; k += 256) {
    float lgk = lg[k];
    float e = __expf(fmaf(20.0f, lgk, of[k])) * cs[k];
    float M = e * fac;
    orow[k] = M;
    Z += __expf((lgk - mx) * qs);
    dot += M * (lgk * qs);
  }
  Z = block_reduce_sum(Z, sbuf);
  dot = block_reduce_sum(dot, sbuf);
  if (threadIdx.x == 0) {
    float lossr = -(dot - sumtgt * (mx * qs + logf(Z)));
    atomicAdd(loss_acc, (double)lossr);
  }
}

__global__ void finalize_loss(const double* __restrict__ loss_acc, float* __restrict__ out_loss) {
  if (threadIdx.x == 0 && blockIdx.x == 0)
    *out_loss = (float)(*loss_acc / (double)ROWS);
}

extern "C" void kernel_launch(void* const* d_in, const int* in_sizes, int n_in,
                              void* d_out, int out_size, void* d_ws, size_t ws_size,
                              hipStream_t stream) {
  const float* x = (const float*)d_in[0];
  const float* W = (const float*)d_in[1];
  float* out = (float*)d_out;
  char* ws = (char*)d_ws;

  // ws layout (~590 MB total)
  float* logits = (float*)ws;                                   // 536,870,912 B
  float* xn     = (float*)(ws + 536870912ull);                  // 50,331,648 B
  float* offv   = (float*)(ws + 536870912ull + 50331648ull);    // 4*8192*4
  float* CS     = offv + S_DIM * K_DIM;
  float* RS     = CS + S_DIM * K_DIM;
  float* pbuf   = RS + ROWS;                                    // 16*4*8192*4 = 2MB
  double* loss_acc = (double*)(pbuf + BCHUNK * S_DIM * K_DIM);

  hipMemsetAsync(loss_acc, 0, sizeof(double), stream);

  normalize_rows<<<ROWS, 256, 0, stream>>>(x, xn);

  dim3 gg(K_DIM / 64, ROWS / 64);
  gemm_nt<<<gg, 256, 0, stream>>>(xn, W, logits);

  dim3 gc(K_DIM / 256, BCHUNK, S_DIM);
  dim3 gv((S_DIM * K_DIM) / 256);
  dim3 gr(B_DIM, S_DIM);

  col_max_partial<<<gc, 256, 0, stream>>>(logits, pbuf);
  col_max_reduce<<<gv, 256, 0, stream>>>(pbuf, offv);

  // c1
  col_sum_partial<<<gc, 256, 0, stream>>>(logits, offv, RS, 0, pbuf);
  col_sum_reduce<<<gv, 256, 0, stream>>>(pbuf, CS, 1);
  // r1
  row_pass<<<gr, 256, 0, stream>>>(logits, offv, CS, RS, 1);
  // c2
  col_sum_partial<<<gc, 256, 0, stream>>>(logits, offv, RS, 1, pbuf);
  col_sum_reduce<<<gv, 256, 0, stream>>>(pbuf, CS, 0);
  // r2
  row_pass<<<gr, 256, 0, stream>>>(logits, offv, CS, RS, 0);
  // c3
  col_sum_partial<<<gc, 256, 0, stream>>>(logits, offv, RS, 1, pbuf);
  col_sum_reduce<<<gv, 256, 0, stream>>>(pbuf, CS, 0);
  // r3 + outputs + loss
  final_pass<<<gr, 256, 0, stream>>>(logits, offv, CS, RS, out, loss_acc);
  finalize_loss<<<1, 64, 0, stream>>>(loss_acc, out + (out_size - 1));
}

// Round 2
// 2032.982 us; speedup vs baseline: 2.0568x; 2.0568x over previous
//
#include <hip/hip_runtime.h>
#include <math.h>

// OnlineClustering: x[4,4096,768] f32, W[8192,768] f32
// out = assignments[4,4096,8192] f32 ++ loss[1] f32
//
// R2: split-bf16 MFMA GEMM (hi/lo, 3 products == fp32-accuracy logits),
//     m97-style 128x128 tile + global_load_lds(16B) staging.
//     final_pass reads logits once (register-cached row).

#define S_DIM 4
#define B_DIM 4096
#define D_DIM 768
#define K_DIM 8192
#define ROWS (S_DIM * B_DIM)   // 16384
#define BCHUNK 16
#define BPER (B_DIM / BCHUNK)  // 256
#define SK_EPS 1e-8f

typedef unsigned short ushort_t;
typedef __attribute__((ext_vector_type(8))) short short8;
typedef __attribute__((ext_vector_type(4))) float f32x4;

__device__ __forceinline__ ushort_t f2bf_rne(float f) {
  union { float f; unsigned u; } c; c.f = f;
  unsigned u = c.u;
  unsigned r = u + 0x7FFFu + ((u >> 16) & 1u);
  return (ushort_t)(r >> 16);
}
__device__ __forceinline__ float bf2f(ushort_t h) {
  union { unsigned u; float f; } c; c.u = ((unsigned)h) << 16;
  return c.f;
}

__device__ __forceinline__ float block_reduce_sum(float v, float* sbuf) {
  #pragma unroll
  for (int off = 32; off > 0; off >>= 1) v += __shfl_down(v, off, 64);
  int lane = threadIdx.x & 63, wid = threadIdx.x >> 6;
  __syncthreads();
  if (lane == 0) sbuf[wid] = v;
  __syncthreads();
  return sbuf[0] + sbuf[1] + sbuf[2] + sbuf[3];
}

__device__ __forceinline__ float block_reduce_max(float v, float* sbuf) {
  #pragma unroll
  for (int off = 32; off > 0; off >>= 1) v = fmaxf(v, __shfl_down(v, off, 64));
  int lane = threadIdx.x & 63, wid = threadIdx.x >> 6;
  __syncthreads();
  if (lane == 0) sbuf[wid] = v;
  __syncthreads();
  return fmaxf(fmaxf(sbuf[0], sbuf[1]), fmaxf(sbuf[2], sbuf[3]));
}

// ---------------- K0a: L2-normalize rows of x, emit bf16 hi/lo split ----------------
__global__ __launch_bounds__(256) void normalize_split(const float* __restrict__ x,
                                                       ushort_t* __restrict__ Ahi,
                                                       ushort_t* __restrict__ Alo) {
  __shared__ float sbuf[4];
  size_t row = blockIdx.x;
  const float* xr = x + row * D_DIM;
  float ss = 0.f;
  for (int i = threadIdx.x; i < D_DIM; i += 256) { float v = xr[i]; ss += v * v; }
  ss = block_reduce_sum(ss, sbuf);
  float inv = 1.0f / fmaxf(sqrtf(ss), 1e-7f);
  for (int i = threadIdx.x; i < D_DIM; i += 256) {
    float v = xr[i] * inv;
    ushort_t h = f2bf_rne(v);
    Ahi[row * D_DIM + i] = h;
    Alo[row * D_DIM + i] = f2bf_rne(v - bf2f(h));
  }
}

// ---------------- K0b: bf16 hi/lo split of W ----------------
__global__ __launch_bounds__(256) void split_w(const float* __restrict__ W,
                                               ushort_t* __restrict__ Whi,
                                               ushort_t* __restrict__ Wlo, int n4) {
  int i = blockIdx.x * 256 + threadIdx.x;
  if (i >= n4) return;
  float4 wv = ((const float4*)W)[i];
  float v[4] = {wv.x, wv.y, wv.z, wv.w};
  ushort4 h, l;
  ushort_t hh[4], ll[4];
  #pragma unroll
  for (int c = 0; c < 4; c++) {
    hh[c] = f2bf_rne(v[c]);
    ll[c] = f2bf_rne(v[c] - bf2f(hh[c]));
  }
  h.x = hh[0]; h.y = hh[1]; h.z = hh[2]; h.w = hh[3];
  l.x = ll[0]; l.y = ll[1]; l.z = ll[2]; l.w = ll[3];
  ((ushort4*)Whi)[i] = h;
  ((ushort4*)Wlo)[i] = l;
}

// ---------------- K1: MFMA GEMM  C[M,N] = A[M,768] * B[N,768]^T (split bf16) ----------
// BM=BN=128, BK=32, 256 threads (4 waves, 2x2 of 64x64), 16x16x32 bf16 MFMA.
__global__ __launch_bounds__(256, 2) void gemm_mfma(const ushort_t* __restrict__ Ahi,
                                                    const ushort_t* __restrict__ Alo,
                                                    const ushort_t* __restrict__ Bhi,
                                                    const ushort_t* __restrict__ Blo,
                                                    float* __restrict__ C) {
  __shared__ __align__(16) ushort_t sAhi[128 * 32];
  __shared__ __align__(16) ushort_t sAlo[128 * 32];
  __shared__ __align__(16) ushort_t sBhi[128 * 32];
  __shared__ __align__(16) ushort_t sBlo[128 * 32];

  const int tid = threadIdx.x;
  const int w = tid >> 6, lane = tid & 63;

  // block swizzle: groups of 8 M-blocks sweep all N for L2 reuse
  int bid = blockIdx.y * gridDim.x + blockIdx.x;
  int grp = bid / (8 * 64);
  int rem = bid % (8 * 64);
  int by = grp * 8 + (rem & 7);
  int bx = rem >> 3;
  const int bm = by * 128, bn = bx * 128;
  const int wm = (w >> 1) * 64, wn = (w & 1) * 64;

  f32x4 acc[4][4] = {};

  // staging: per wave, per array, 2 calls of 16 rows x 32 k (1 KB each)
  const int srow = w * 32 + (lane >> 2);     // + c*16
  const int skof = (lane & 3) * 8;
  const size_t gAbase = (size_t)(bm + srow) * D_DIM + skof;
  const size_t gBbase = (size_t)(bn + srow) * D_DIM + skof;

  // loop-invariant fragment LDS offsets (elements)
  const int q8 = (lane >> 4) * 8;
  int aoff[4], boff[4];
  #pragma unroll
  for (int i = 0; i < 4; i++) aoff[i] = (wm + i * 16 + (lane & 15)) * 32 + q8;
  #pragma unroll
  for (int j = 0; j < 4; j++) boff[j] = (wn + j * 16 + (lane & 15)) * 32 + q8;

  for (int k0 = 0; k0 < D_DIM; k0 += 32) {
    #pragma unroll
    for (int c = 0; c < 2; c++) {
      const int lofs = (w * 32 + c * 16) * 32;
      const size_t go = (size_t)c * 16 * D_DIM + k0;
      __builtin_amdgcn_global_load_lds(
          (const __attribute__((address_space(1))) void*)(Ahi + gAbase + go),
          (__attribute__((address_space(3))) void*)(sAhi + lofs), 16, 0, 0);
      __builtin_amdgcn_global_load_lds(
          (const __attribute__((address_space(1))) void*)(Alo + gAbase + go),
          (__attribute__((address_space(3))) void*)(sAlo + lofs), 16, 0, 0);
      __builtin_amdgcn_global_load_lds(
          (const __attribute__((address_space(1))) void*)(Bhi + gBbase + go),
          (__attribute__((address_space(3))) void*)(sBhi + lofs), 16, 0, 0);
      __builtin_amdgcn_global_load_lds(
          (const __attribute__((address_space(1))) void*)(Blo + gBbase + go),
          (__attribute__((address_space(3))) void*)(sBlo + lofs), 16, 0, 0);
    }
    __syncthreads();

    short8 ah[4], al[4], bh[4], bl[4];
    #pragma unroll
    for (int i = 0; i < 4; i++) {
      ah[i] = *(const short8*)(sAhi + aoff[i]);
      al[i] = *(const short8*)(sAlo + aoff[i]);
    }
    #pragma unroll
    for (int j = 0; j < 4; j++) {
      bh[j] = *(const short8*)(sBhi + boff[j]);
      bl[j] = *(const short8*)(sBlo + boff[j]);
    }
    #pragma unroll
    for (int i = 0; i < 4; i++)
      #pragma unroll
      for (int j = 0; j < 4; j++) {
        acc[i][j] = __builtin_amdgcn_mfma_f32_16x16x32_bf16(ah[i], bh[j], acc[i][j], 0, 0, 0);
        acc[i][j] = __builtin_amdgcn_mfma_f32_16x16x32_bf16(ah[i], bl[j], acc[i][j], 0, 0, 0);
        acc[i][j] = __builtin_amdgcn_mfma_f32_16x16x32_bf16(al[i], bh[j], acc[i][j], 0, 0, 0);
      }
    __syncthreads();
  }

  // epilogue: C/D layout col=lane&15, row=(lane>>4)*4+reg
  const int col0 = bn + wn + (lane & 15);
  const int row0 = bm + wm + (lane >> 4) * 4;
  #pragma unroll
  for (int i = 0; i < 4; i++)
    #pragma unroll
    for (int r = 0; r < 4; r++) {
      size_t rowoff = (size_t)(row0 + i * 16 + r) * K_DIM;
      #pragma unroll
      for (int j = 0; j < 4; j++)
        C[rowoff + col0 + j * 16] = acc[i][j][r];
    }
}

// ---------------- K2: column max partials (over b) ----------------
__global__ __launch_bounds__(256) void col_max_partial(const float* __restrict__ logits,
                                                       float* __restrict__ pbuf) {
  int k = blockIdx.x * 256 + threadIdx.x;
  int chunk = blockIdx.y, s = blockIdx.z;
  const float* base = logits + ((size_t)s * B_DIM + (size_t)chunk * BPER) * K_DIM + k;
  float mx = -INFINITY;
  #pragma unroll 4
  for (int b = 0; b < BPER; b++) mx = fmaxf(mx, base[(size_t)b * K_DIM]);
  pbuf[((size_t)chunk * S_DIM + s) * K_DIM + k] = mx;
}

__global__ __launch_bounds__(256) void col_max_reduce(const float* __restrict__ pbuf,
                                                      float* __restrict__ offv) {
  int i = blockIdx.x * 256 + threadIdx.x;  // i = s*K_DIM + k
  int s = i >> 13, k = i & (K_DIM - 1);
  float mx = -INFINITY;
  for (int c = 0; c < BCHUNK; c++) mx = fmaxf(mx, pbuf[((size_t)c * S_DIM + s) * K_DIM + k]);
  offv[i] = 50.0f - 20.0f * mx;
}

// ---------------- column sum partials: sum_b E * (RS[b] or 1) ----------------
__global__ __launch_bounds__(256) void col_sum_partial(const float* __restrict__ logits,
                                                       const float* __restrict__ offv,
                                                       const float* __restrict__ RS, int use_rs,
                                                       float* __restrict__ pbuf) {
  int k = blockIdx.x * 256 + threadIdx.x;
  int chunk = blockIdx.y, s = blockIdx.z;
  const float off = offv[(size_t)s * K_DIM + k];
  const float* base = logits + ((size_t)s * B_DIM + (size_t)chunk * BPER) * K_DIM + k;
  const float* rs = RS + (size_t)s * B_DIM + (size_t)chunk * BPER;
  float sum = 0.f;
  #pragma unroll 4
  for (int b = 0; b < BPER; b++) {
    float e = __expf(fmaf(20.0f, base[(size_t)b * K_DIM], off));
    float rfac = use_rs ? rs[b] : 1.0f;
    sum += e * rfac;
  }
  pbuf[((size_t)chunk * S_DIM + s) * K_DIM + k] = sum;
}

__global__ __launch_bounds__(256) void col_sum_reduce(const float* __restrict__ pbuf,
                                                      float* __restrict__ CS, int init) {
  int i = blockIdx.x * 256 + threadIdx.x;
  int s = i >> 13, k = i & (K_DIM - 1);
  float ssum = 0.f;
  for (int c = 0; c < BCHUNK; c++) ssum += pbuf[((size_t)c * S_DIM + s) * K_DIM + k];
  float old = init ? 1.0f : CS[i];
  CS[i] = old / (fmaf(old, ssum, SK_EPS));
}

// ---------------- row pass ----------------
__global__ __launch_bounds__(256) void row_pass(const float* __restrict__ logits,
                                                const float* __restrict__ offv,
                                                const float* __restrict__ CS,
                                                float* __restrict__ RS, int init) {
  __shared__ float sbuf[4];
  int b = blockIdx.x, s = blockIdx.y;
  size_t row = (size_t)s * B_DIM + b;
  const float* lg = logits + row * K_DIM;
  const float* of = offv + (size_t)s * K_DIM;
  const float* cs = CS + (size_t)s * K_DIM;
  float sum = 0.f;
  #pragma unroll 4
  for (int k = threadIdx.x; k < K_DIM; k += 256) {
    float e = __expf(fmaf(20.0f, lg[k], of[k]));
    sum += e * cs[k];
  }
  sum = block_reduce_sum(sum, sbuf);
  if (threadIdx.x == 0) {
    float old = init ? 1.0f : RS[row];
    RS[row] = old / fmaf(old, sum, SK_EPS);
  }
}

// ---------------- final: r3 + write assignments + loss (single logits read) ----------
__global__ __launch_bounds__(256) void final_pass(const float* __restrict__ logits,
                                                  const float* __restrict__ offv,
                                                  const float* __restrict__ CS,
                                                  const float* __restrict__ RS,
                                                  float* __restrict__ out,
                                                  double* __restrict__ loss_acc) {
  __shared__ float sbuf[4];
  int b = blockIdx.x, s = blockIdx.y;
  size_t row = (size_t)s * B_DIM + b;
  const float* lg = logits + row * K_DIM;
  const float* of = offv + (size_t)s * K_DIM;
  const float* cs = CS + (size_t)s * K_DIM;
  const int t = threadIdx.x;

  float v[32], ecs[32];
  float sum = 0.f, mx = -INFINITY;
  #pragma unroll
  for (int i = 0; i < 8; i++) {
    float4 lv = *(const float4*)&lg[t * 4 + i * 1024];
    float4 ov = *(const float4*)&of[t * 4 + i * 1024];
    float4 cv = *(const float4*)&cs[t * 4 + i * 1024];
    float vv[4] = {lv.x, lv.y, lv.z, lv.w};
    float oo[4] = {ov.x, ov.y, ov.z, ov.w};
    float cc[4] = {cv.x, cv.y, cv.z, cv.w};
    #pragma unroll
    for (int c = 0; c < 4; c++) {
      v[i * 4 + c] = vv[c];
      float e = __expf(fmaf(20.0f, vv[c], oo[c])) * cc[c];
      ecs[i * 4 + c] = e;
      sum += e;
      mx = fmaxf(mx, vv[c]);
    }
  }
  sum = block_reduce_sum(sum, sbuf);
  mx = block_reduce_max(mx, sbuf);

  float r = RS[row];
  float rowsum = r * sum;
  float r3 = 1.0f / (rowsum + SK_EPS);
  float fac = r * r3;
  float sumtgt = rowsum * r3;
  const float qs = 1.0f / 0.12f;

  float Z = 0.f, dot = 0.f;
  float* orow = out + row * K_DIM;
  #pragma unroll
  for (int i = 0; i < 8; i++) {
    float m4[4];
    #pragma unroll
    for (int c = 0; c < 4; c++) {
      float M = ecs[i * 4 + c] * fac;
      m4[c] = M;
      Z += __expf((v[i * 4 + c] - mx) * qs);
      dot += M * (v[i * 4 + c] * qs);
    }
    float4 o = {m4[0], m4[1], m4[2], m4[3]};
    *(float4*)&orow[t * 4 + i * 1024] = o;
  }
  Z = block_reduce_sum(Z, sbuf);
  dot = block_reduce_sum(dot, sbuf);
  if (t == 0) {
    float lossr = -(dot - sumtgt * (mx * qs + logf(Z)));
    atomicAdd(loss_acc, (double)lossr);
  }
}

__global__ void finalize_loss(const double* __restrict__ loss_acc, float* __restrict__ out_loss) {
  if (threadIdx.x == 0 && blockIdx.x == 0)
    *out_loss = (float)(*loss_acc / (double)ROWS);
}

extern "C" void kernel_launch(void* const* d_in, const int* in_sizes, int n_in,
                              void* d_out, int out_size, void* d_ws, size_t ws_size,
                              hipStream_t stream) {
  const float* x = (const float*)d_in[0];
  const float* W = (const float*)d_in[1];
  float* out = (float*)d_out;
  char* ws = (char*)d_ws;

  // ws layout
  float* logits   = (float*)ws;                                   // 536,870,912 B
  char* p = ws + 536870912ull;
  ushort_t* Ahi = (ushort_t*)p;  p += (size_t)ROWS * D_DIM * 2;   // 25,165,824
  ushort_t* Alo = (ushort_t*)p;  p += (size_t)ROWS * D_DIM * 2;
  ushort_t* Whi = (ushort_t*)p;  p += (size_t)K_DIM * D_DIM * 2;  // 12,582,912
  ushort_t* Wlo = (ushort_t*)p;  p += (size_t)K_DIM * D_DIM * 2;
  float* offv = (float*)p;       p += (size_t)S_DIM * K_DIM * 4;
  float* CS   = (float*)p;       p += (size_t)S_DIM * K_DIM * 4;
  float* RS   = (float*)p;       p += (size_t)ROWS * 4;
  float* pbuf = (float*)p;       p += (size_t)BCHUNK * S_DIM * K_DIM * 4;
  double* loss_acc = (double*)p;

  hipMemsetAsync(loss_acc, 0, sizeof(double), stream);

  normalize_split<<<ROWS, 256, 0, stream>>>(x, Ahi, Alo);
  split_w<<<(K_DIM * D_DIM / 4 + 255) / 256, 256, 0, stream>>>(W, Whi, Wlo, K_DIM * D_DIM / 4);

  dim3 gg(K_DIM / 128, ROWS / 128);  // (64, 128)
  gemm_mfma<<<gg, 256, 0, stream>>>(Ahi, Alo, Whi, Wlo, logits);

  dim3 gc(K_DIM / 256, BCHUNK, S_DIM);
  dim3 gv((S_DIM * K_DIM) / 256);
  dim3 gr(B_DIM, S_DIM);

  col_max_partial<<<gc, 256, 0, stream>>>(logits, pbuf);
  col_max_reduce<<<gv, 256, 0, stream>>>(pbuf, offv);

  // c1
  col_sum_partial<<<gc, 256, 0, stream>>>(logits, offv, RS, 0, pbuf);
  col_sum_reduce<<<gv, 256, 0, stream>>>(pbuf, CS, 1);
  // r1
  row_pass<<<gr, 256, 0, stream>>>(logits, offv, CS, RS, 1);
  // c2
  col_sum_partial<<<gc, 256, 0, stream>>>(logits, offv, RS, 1, pbuf);
  col_sum_reduce<<<gv, 256, 0, stream>>>(pbuf, CS, 0);
  // r2
  row_pass<<<gr, 256, 0, stream>>>(logits, offv, CS, RS, 0);
  // c3
  col_sum_partial<<<gc, 256, 0, stream>>>(logits, offv, RS, 1, pbuf);
  col_sum_reduce<<<gv, 256, 0, stream>>>(pbuf, CS, 0);
  // r3 + outputs + loss
  final_pass<<<gr, 256, 0, stream>>>(logits, offv, CS, RS, out, loss_acc);
  finalize_loss<<<1, 64, 0, stream>>>(loss_acc, out + (out_size - 1));
}